// Round 10
// baseline (33256.247 us; speedup 1.0000x reference)
//
#include <hip/hip_runtime.h>
#include <hip/hip_cooperative_groups.h>

namespace cg = cooperative_groups;

#define Bb   256   // batch
#define Tt   512   // time steps
#define INx  19    // input features
#define Hh   512   // hidden
#define NWG  256   // workgroups (2 units each) -- cooperative-launch proven size
#define NTHR 512   // 8 waves = (kq 0..3) x (su 0..1); lane = bg 0..63 (4 batches)

#define PART_FLOATS (8 * 12 * 256)       // [su*4+kq][12 rows][256 b] = 98304 B
#define WX1_FLOATS  (8 * 20)             // 2 units x 4 gates x 19 (pad 20)
#define FCB_FLOATS  (Hh + 256 + 128)
#define SMEM_FLOATS (PART_FLOATS + WX1_FLOATS + FCB_FLOATS)
#define SMEM_BYTES  (SMEM_FLOATS * 4)

typedef unsigned int u32;
typedef unsigned long long u64;

__device__ __forceinline__ float sigf(float x) { return 1.0f / (1.0f + __expf(-x)); }
__device__ __forceinline__ float tanhfast(float x) {
    float e = __expf(2.0f * x);
    return 1.0f - 2.0f / (e + 1.0f);
}

// h stores are PLAIN cached stores (stay in cache hierarchy; LLC-visible after
// the release fence in gbar). The r9 agent-atomic stores bypassed LLC to HBM
// -> every post-fence h read was an ~900cy HBM miss (hbm_bytes 5.6 MB/step).
__device__ __forceinline__ void gstore2(float2* p, float2 v) { *p = v; }

// Release: syncthreads (drain vmcnt) -> wbl2 (dirty h -> LLC) -> flag.
// Acquire: poll flags -> buffer_inv (L1/L2) -> cached h reads refill from LLC.
__device__ __forceinline__ void gbar(u32* flags, int wgid, int tid, u32 phase) {
    __syncthreads();   // all waves' h stores drained to L2
    if (tid == 0) {
        __builtin_amdgcn_fence(__ATOMIC_RELEASE, "agent");   // buffer_wbl2
        __hip_atomic_store(&flags[wgid], phase, __ATOMIC_RELEASE, __HIP_MEMORY_SCOPE_AGENT);
    }
    if (tid < NWG) {
        const u32* fp = &flags[tid];
        while (__hip_atomic_load(fp, __ATOMIC_RELAXED, __HIP_MEMORY_SCOPE_AGENT) < phase)
            __builtin_amdgcn_s_sleep(2);
    }
    __syncthreads();
    __builtin_amdgcn_fence(__ATOMIC_ACQUIRE, "agent");   // L1/L2 inv -> LLC refill
}

// load chunk c: 4 consecutive k's, this lane's 4 batches as 2 float4 per k
__device__ __forceinline__ void ldh(const float4* __restrict__ hp, int c,
                                    float4 (&A)[4], float4 (&B)[4]) {
    #pragma unroll
    for (int kk = 0; kk < 4; ++kk) {
        A[kk] = hp[(size_t)(c * 4 + kk) * 128];
        B[kk] = hp[(size_t)(c * 4 + kk) * 128 + 1];
    }
}

// 192 FMA: 12 rows x 4 k x 4 batches. Weight pointers are WAVE-UNIFORM
// (built from readfirstlane'd su/kq) -> s_load_dwordx4, SGPR operands.
// A[kk]: batches b0,b1 as (h1,h2,h1,h2); B[kk]: b2,b3.
__device__ __forceinline__ void fmac(const float4 (&A)[4], const float4 (&B)[4],
                                     const float* const (&wb1)[4],
                                     const float* const (&wb2)[4],
                                     const float* const (&wb3)[4], int c4,
                                     float (&a1)[4][4], float (&ax)[4][4], float (&ah)[4][4]) {
    #pragma unroll
    for (int g = 0; g < 4; ++g) {
        const float4 w1 = *reinterpret_cast<const float4*>(wb1[g] + c4);
        const float4 w2 = *reinterpret_cast<const float4*>(wb2[g] + c4);
        const float4 w3 = *reinterpret_cast<const float4*>(wb3[g] + c4);
        a1[g][0] += A[0].x*w1.x + A[1].x*w1.y + A[2].x*w1.z + A[3].x*w1.w;
        a1[g][1] += A[0].z*w1.x + A[1].z*w1.y + A[2].z*w1.z + A[3].z*w1.w;
        a1[g][2] += B[0].x*w1.x + B[1].x*w1.y + B[2].x*w1.z + B[3].x*w1.w;
        a1[g][3] += B[0].z*w1.x + B[1].z*w1.y + B[2].z*w1.z + B[3].z*w1.w;
        ax[g][0] += A[0].x*w2.x + A[1].x*w2.y + A[2].x*w2.z + A[3].x*w2.w;
        ax[g][1] += A[0].z*w2.x + A[1].z*w2.y + A[2].z*w2.z + A[3].z*w2.w;
        ax[g][2] += B[0].x*w2.x + B[1].x*w2.y + B[2].x*w2.z + B[3].x*w2.w;
        ax[g][3] += B[0].z*w2.x + B[1].z*w2.y + B[2].z*w2.z + B[3].z*w2.w;
        ah[g][0] += A[0].y*w3.x + A[1].y*w3.y + A[2].y*w3.z + A[3].y*w3.w;
        ah[g][1] += A[0].w*w3.x + A[1].w*w3.y + A[2].w*w3.z + A[3].w*w3.w;
        ah[g][2] += B[0].y*w3.x + B[1].y*w3.y + B[2].y*w3.z + B[3].y*w3.w;
        ah[g][3] += B[0].w*w3.x + B[1].w*w3.y + B[2].w*w3.z + B[3].w*w3.w;
    }
}

__global__ void __launch_bounds__(NTHR, 2)
lstm_fused(const float* __restrict__ input,
           const float* __restrict__ l1_Wx, const float* __restrict__ l1_bx,
           const float* __restrict__ l1_Wh, const float* __restrict__ l1_bh,
           const float* __restrict__ l2_Wx, const float* __restrict__ l2_bx,
           const float* __restrict__ l2_Wh, const float* __restrict__ l2_bh,
           const float* __restrict__ fc1_W, const float* __restrict__ fc1_b,
           const float* __restrict__ fc2_W, const float* __restrict__ fc2_b,
           const float* __restrict__ fc3_W, const float* __restrict__ fc3_b,
           float* __restrict__ out, float* __restrict__ ws)
{
    extern __shared__ float smem[];
    float* part = smem;                        // [8][12][256] K-partial exchange
    float* wx1l = smem + PART_FLOATS;          // [2u][4g][20]
    float* fcb  = wx1l + WX1_FLOATS;

    cg::grid_group grid = cg::this_grid();
    const int wgid = blockIdx.x;
    const int jb = wgid * 2;
    const int tid = threadIdx.x;

    // sweep role: wave (su, kq), lane bg -> batches bg*4..+3, K quarter kq
    const int wu = __builtin_amdgcn_readfirstlane(tid >> 6);   // wave id, uniform
    const int su = wu & 1;           // unit select
    const int kq = wu >> 1;          // K quarter
    const int bg = tid & 63;
    // finish role: thread (su2, fb) -> unit jb+su2, batch fb
    const int su2 = tid >> 8;
    const int fb  = tid & 255;
    const int j2  = jb + su2;

    float2* PA = (float2*)ws;        // P[j][b] = (h1, h2)
    float2* PB = PA + Hh * Bb;
    u32* flags = (u32*)(PB + Hh * Bb);

    if (tid == 0)
        __hip_atomic_store(&flags[wgid], 0u, __ATOMIC_RELAXED, __HIP_MEMORY_SCOPE_AGENT);
    grid.sync();   // fences flag resets; the only runtime cg sync

    // ---- wave-uniform scalar weight row bases (s_load path) ----
    const float* wb1[4]; const float* wb2[4]; const float* wb3[4];
    {
        const int j = jb + su;
        #pragma unroll
        for (int g = 0; g < 4; ++g) {
            const size_t off = (size_t)(g * Hh + j) * Hh + kq * 128;
            wb1[g] = l1_Wh + off;
            wb2[g] = l2_Wx + off;
            wb3[g] = l2_Wh + off;
        }
    }

    // ---- stage tiny l1_Wx + biases (finish role) ----
    if (tid < 8 * INx) {
        const int r = tid / INx, i = tid - r * INx;
        const int u = r >> 2, g = r & 3;
        wx1l[r * 20 + i] = l1_Wx[(size_t)(g * Hh + jb + u) * INx + i];
    }
    float b1r[4], b2r[4];
    #pragma unroll
    for (int g = 0; g < 4; ++g) {
        const int row = g * Hh + j2;
        b1r[g] = l1_bx[row] + l1_bh[row];
        b2r[g] = l2_bx[row] + l2_bh[row];
    }
    __syncthreads();

    // ---- prologue: P = (h1[0], h2[-1]=0), finish role ----
    float c1 = 0.f, c2 = 0.f;
    {
        const float* xr = input + (size_t)fb * Tt * INx;
        float s[4];
        #pragma unroll
        for (int g = 0; g < 4; ++g) {
            float acc = b1r[g];
            #pragma unroll
            for (int i = 0; i < INx; ++i) acc += xr[i] * wx1l[(su2 * 4 + g) * 20 + i];
            s[g] = acc;
        }
        c1 = sigf(s[0]) * tanhfast(s[2]);
        gstore2(&PA[(size_t)j2 * Bb + fb], make_float2(sigf(s[3]) * tanhfast(c1), 0.f));
    }
    gbar(flags, wgid, tid, 1u);

    const float2* Pc = PA; float2* Pn = PB;
    const int blk = su * 4 + kq;     // partial rowset for this wave

    for (int t = 0; t < Tt; ++t) {
        const bool doL1 = (t < Tt - 1);

        float a1[4][4], ax[4][4], ah[4][4];
        #pragma unroll
        for (int g = 0; g < 4; ++g)
            #pragma unroll
            for (int b = 0; b < 4; ++b) { a1[g][b] = 0.f; ax[g][b] = 0.f; ah[g][b] = 0.f; }

        // lane's float4 base: f4 index = k*128 + bg*2, k = kq*128 + ...
        const float4* hp = (const float4*)Pc + (size_t)(kq * 128) * 128 + bg * 2;

        float4 E0[4], E1[4], O0[4], O1[4];
        ldh(hp, 0, E0, E1);
        #pragma unroll 1
        for (int c = 0; c < 32; c += 2) {
            ldh(hp, c + 1, O0, O1);
            fmac(E0, E1, wb1, wb2, wb3, (c    ) * 4, a1, ax, ah);
            if (c < 30) ldh(hp, c + 2, E0, E1);
            fmac(O0, O1, wb1, wb2, wb3, (c + 1) * 4, a1, ax, ah);
        }

        // ---- K-partial exchange: ds_write_b128, conflict-free ----
        {
            float* pw = part + (size_t)(blk * 12) * 256 + bg * 4;
            #pragma unroll
            for (int g = 0; g < 4; ++g) {
                *reinterpret_cast<float4*>(pw + (0 + g) * 256) = make_float4(a1[g][0], a1[g][1], a1[g][2], a1[g][3]);
                *reinterpret_cast<float4*>(pw + (4 + g) * 256) = make_float4(ax[g][0], ax[g][1], ax[g][2], ax[g][3]);
                *reinterpret_cast<float4*>(pw + (8 + g) * 256) = make_float4(ah[g][0], ah[g][1], ah[g][2], ah[g][3]);
            }
        }
        __syncthreads();

        // ---- finish: unit j2, batch fb; reduce 4 kq rowsets ----
        {
            float s1[4], s2[4];
            #pragma unroll
            for (int g = 0; g < 4; ++g) {
                float A1 = 0.f, AX = 0.f, AH = 0.f;
                #pragma unroll
                for (int q = 0; q < 4; ++q) {
                    const float* pr = part + (size_t)((su2 * 4 + q) * 12) * 256 + fb;
                    A1 += pr[(0 + g) * 256];
                    AX += pr[(4 + g) * 256];
                    AH += pr[(8 + g) * 256];
                }
                s1[g] = A1 + b1r[g];
                s2[g] = AX + AH + b2r[g];
            }
            float h1v = 0.f;
            if (doL1) {
                const float* xr = input + ((size_t)fb * Tt + t + 1) * INx;
                #pragma unroll
                for (int g = 0; g < 4; ++g) {
                    float acc = s1[g];
                    #pragma unroll
                    for (int i = 0; i < INx; ++i) acc += xr[i] * wx1l[(su2 * 4 + g) * 20 + i];
                    s1[g] = acc;
                }
                const float ig = sigf(s1[0]), fg = sigf(s1[1]);
                const float gg = tanhfast(s1[2]), og = sigf(s1[3]);
                c1 = fg * c1 + ig * gg;
                h1v = og * tanhfast(c1);
            }
            const float ig = sigf(s2[0]), fg = sigf(s2[1]);
            const float gg = tanhfast(s2[2]), og = sigf(s2[3]);
            c2 = fg * c2 + ig * gg;
            gstore2(&Pn[(size_t)j2 * Bb + fb], make_float2(h1v, og * tanhfast(c2)));
        }

        gbar(flags, wgid, tid, (u32)(t + 2));

        const float2* tp = Pc; Pc = Pn; Pn = (float2*)tp;
    }
    // final h2 = Pc[.].y

    // ---------- FC head: WG wgid handles batch wgid (reuse smem) ----------
    float* hh  = fcb;
    float* a1s = fcb + Hh;
    float* a2s = fcb + Hh + 256;
    hh[tid] = Pc[(size_t)tid * Bb + wgid].y;   // cached, fresh post-fence
    __syncthreads();
    if (tid < 256) {
        float acc = fc1_b[tid];
        const float* wr = fc1_W + (size_t)tid * Hh;
        for (int i = 0; i < Hh; ++i) acc += wr[i] * hh[i];
        a1s[tid] = fmaxf(acc, 0.0f);
    }
    __syncthreads();
    if (tid < 128) {
        float acc = fc2_b[tid];
        const float* wr = fc2_W + (size_t)tid * 256;
        for (int i = 0; i < 256; ++i) acc += wr[i] * a1s[i];
        a2s[tid] = fmaxf(acc, 0.0f);
    }
    __syncthreads();
    if (tid == 0) {
        float acc = fc3_b[0];
        for (int i = 0; i < 128; ++i) acc += fc3_W[i] * a2s[i];
        out[wgid] = acc;
    }
}

extern "C" void kernel_launch(void* const* d_in, const int* in_sizes, int n_in,
                              void* d_out, int out_size, void* d_ws, size_t ws_size,
                              hipStream_t stream)
{
    (void)in_sizes; (void)n_in; (void)out_size; (void)ws_size;

    const float* input = (const float*)d_in[0];
    const float* l1_Wx = (const float*)d_in[1];
    const float* l1_bx = (const float*)d_in[2];
    const float* l1_Wh = (const float*)d_in[3];
    const float* l1_bh = (const float*)d_in[4];
    const float* l2_Wx = (const float*)d_in[5];
    const float* l2_bx = (const float*)d_in[6];
    const float* l2_Wh = (const float*)d_in[7];
    const float* l2_bh = (const float*)d_in[8];
    const float* fc1_W = (const float*)d_in[9];
    const float* fc1_b = (const float*)d_in[10];
    const float* fc2_W = (const float*)d_in[11];
    const float* fc2_b = (const float*)d_in[12];
    const float* fc3_W = (const float*)d_in[13];
    const float* fc3_b = (const float*)d_in[14];
    float* out = (float*)d_out;
    float* ws  = (float*)d_ws;

    hipFuncSetAttribute((const void*)lstm_fused,
                        hipFuncAttributeMaxDynamicSharedMemorySize, SMEM_BYTES);

    void* args[] = {
        &input,
        &l1_Wx, &l1_bx, &l1_Wh, &l1_bh,
        &l2_Wx, &l2_bx, &l2_Wh, &l2_bh,
        &fc1_W, &fc1_b, &fc2_W, &fc2_b, &fc3_W, &fc3_b,
        &out, &ws
    };
    hipLaunchCooperativeKernel((void*)lstm_fused, dim3(NWG), dim3(NTHR), args,
                               SMEM_BYTES, stream);
}